// Round 2
// 219.973 us; speedup vs baseline: 1.0625x; 1.0625x over previous
//
#include <hip/hip_runtime.h>
#include <hip/hip_bf16.h>

typedef unsigned short u16;
typedef unsigned int u32;
typedef __bf16 bf16x8 __attribute__((ext_vector_type(8)));
typedef float f32x4 __attribute__((ext_vector_type(4)));
typedef u16 u16x8 __attribute__((ext_vector_type(8)));
typedef u32 u32x2 __attribute__((ext_vector_type(2)));

#define S_LEN 2048
#define DMODEL 512
#define NHEAD 8
#define DHEAD 64
#define KSPLIT 4
#define KRANGE (S_LEN / KSPLIT)  // 512 k-positions per block
// log2(e); Q is pre-scaled by 0.125*LOG2E so softmax runs in exp2 domain.
#define QSCALE 0.1803368801111204f
#define MASKC 1.4426950409e9f
#define RESCALE_THR 8.0f

static __device__ __forceinline__ float bf2f(u16 v) {
    union { unsigned u; float f; } cv; cv.u = ((unsigned)v) << 16; return cv.f;
}
static __device__ __forceinline__ u16 f2bf(float f) {
    union { float f; unsigned u; } cv; cv.f = f;
    unsigned u = cv.u;
    return (u16)((u + 0x7fffu + ((u >> 16) & 1u)) >> 16);  // RNE
}
static __device__ __forceinline__ u32 pk2bf(float a, float b) {
    union { __hip_bfloat162 h; u32 u; } cv;
    float2 f2; f2.x = a; f2.y = b;
    cv.h = __float22bfloat162_rn(f2);
    return cv.u;
}
static __device__ __forceinline__ bf16x8 ld8(const u16* p) {
    return *(const bf16x8*)p;
}
static __device__ __forceinline__ float fmax3(float a, float b, float c) {
    return __builtin_fmaxf(__builtin_fmaxf(a, b), c);  // clang fuses to v_max3_f32
}

// ---------------- fused prep: qkv fp32->bf16 cvt | weight transpose->bf16 | mask flags ----
// grid.x partition: [0,3072) cvt, [3072,4096) transpose_w, [4096,6144) mask flags. 256 thr.
__global__ __launch_bounds__(256) void prep_kernel(
    const float* __restrict__ q, const float* __restrict__ k, const float* __restrict__ v,
    const float* __restrict__ w0, const float* __restrict__ w1,
    const float* __restrict__ w2, const float* __restrict__ w3,
    const float* __restrict__ mask,
    u16* __restrict__ Aqkv, u16* __restrict__ wtall, int* __restrict__ flags) {
    const int p = blockIdx.x;
    const int tid = threadIdx.x;
    __shared__ float t[32][33];
    __shared__ int wred[4];
    if (p < 3072) {
        const int z = p >> 10, px = p & 1023;
        const float* in = (z == 0) ? q : (z == 1) ? k : v;
        u16* o = Aqkv + (long)z * 2097152;
        long i = ((long)px * 256 + tid) * 8;
        f32x4 a = *(const f32x4*)(in + i);
        f32x4 b = *(const f32x4*)(in + i + 4);
        u16x8 r;
#pragma unroll
        for (int j = 0; j < 4; ++j) { r[j] = f2bf(a[j]); r[4 + j] = f2bf(b[j]); }
        *(u16x8*)(o + i) = r;
    } else if (p < 4096) {
        // W (512x512 fp32) -> Wt bf16 (N x K). slot order in wtall: [wo, wq, wk, wv]
        const int p2 = p - 3072;
        const int z = p2 >> 8, rem = p2 & 255, by = rem >> 4, bx = rem & 15;
        const float* in = (z == 0) ? w0 : (z == 1) ? w1 : (z == 2) ? w2 : w3;
        u16* o = wtall + (long)(((z + 1) & 3)) * 262144;
        const int tx = tid & 31, ty = tid >> 5;
#pragma unroll
        for (int i = 0; i < 4; ++i)
            t[ty + 8 * i][tx] = in[(by * 32 + ty + 8 * i) * DMODEL + bx * 32 + tx];
        __syncthreads();
#pragma unroll
        for (int i = 0; i < 4; ++i)
            o[(bx * 32 + ty + 8 * i) * DMODEL + by * 32 + tx] = f2bf(t[tx][ty + 8 * i]);
    } else {
        const int bid = p - 4096;  // 2*32*32
        const int b = bid >> 10, qt = (bid >> 5) & 31, kt = bid & 31;
        const int r = tid >> 2, cs = tid & 3;
        const float* mp = mask + ((long)(b * S_LEN + qt * 64 + r)) * S_LEN + kt * 64 + cs * 16;
        int nz = 0;
#pragma unroll
        for (int j = 0; j < 4; ++j) {
            f32x4 a = *(const f32x4*)(mp + j * 4);
            nz |= (a[0] != 0.f) | (a[1] != 0.f) | (a[2] != 0.f) | (a[3] != 0.f);
        }
        unsigned long long ball = __ballot(nz);
        if ((tid & 63) == 0) wred[tid >> 6] = (ball != 0ull) ? 1 : 0;
        __syncthreads();
        if (tid == 0) flags[bid] = wred[0] | wred[1] | wred[2] | wred[3];
    }
}

// V merged bf16 (B,S,512) -> Vt bf16 (B,H,DH,S)
__global__ void transpose_v_kernel(const u16* __restrict__ V, u16* __restrict__ Vt) {
    int z = blockIdx.z;
    int b = z >> 3, h = z & 7;
    const u16* in = V + (long)b * S_LEN * DMODEL + h * DHEAD;
    u16* out = Vt + (long)z * DHEAD * S_LEN;
    __shared__ u16 t[32][33];
    int tx = threadIdx.x, ty = threadIdx.y;
    int r = blockIdx.y * 32 + ty;  // s
    int c = blockIdx.x * 32 + tx;  // d
    t[ty][tx] = in[(long)r * DMODEL + c];
    __syncthreads();
    int orow = blockIdx.x * 32 + ty;  // d
    int ocol = blockIdx.y * 32 + tx;  // s
    out[(long)orow * S_LEN + ocol] = t[tx][ty];
}

// ---------------- GEMM: C(4096x512) = A(4096x512) @ W + bias; block tile (TM*32) x 64,
// 4 waves (2x2), wave tile (TM*16) x 32.
template <bool F32OUT, int TM>
static __device__ __forceinline__ void gemm_body(const u16* __restrict__ A,
                                                 const u16* __restrict__ Wt,
                                                 const float* __restrict__ bias,
                                                 void* __restrict__ Cp, float oscale) {
    const int lane = threadIdx.x & 63;
    const int wave = threadIdx.x >> 6;
    const int wr = wave >> 1, wc = wave & 1;
    const int m0 = blockIdx.y * (TM * 32) + wr * (TM * 16);
    const int n0 = blockIdx.x * 64 + wc * 32;
    const int cidx = lane & 15;
    const int kg = lane >> 4;

    const u16* aptr[TM];
    const u16* bptr[2];
#pragma unroll
    for (int t = 0; t < TM; ++t)
        aptr[t] = A + (long)(m0 + t * 16 + cidx) * DMODEL + kg * 8;
#pragma unroll
    for (int t = 0; t < 2; ++t)
        bptr[t] = Wt + (long)(n0 + t * 16 + cidx) * DMODEL + kg * 8;

    const f32x4 fz = {0.f, 0.f, 0.f, 0.f};
    f32x4 acc[TM][2];
#pragma unroll
    for (int i = 0; i < TM; ++i)
#pragma unroll
        for (int j = 0; j < 2; ++j) acc[i][j] = fz;

#pragma unroll 4
    for (int k0 = 0; k0 < 512; k0 += 32) {
        bf16x8 a[TM], b[2];
#pragma unroll
        for (int t = 0; t < TM; ++t) a[t] = ld8(aptr[t] + k0);
#pragma unroll
        for (int t = 0; t < 2; ++t) b[t] = ld8(bptr[t] + k0);
#pragma unroll
        for (int i = 0; i < TM; ++i)
#pragma unroll
            for (int j = 0; j < 2; ++j)
                acc[i][j] = __builtin_amdgcn_mfma_f32_16x16x32_bf16(a[i], b[j], acc[i][j], 0, 0, 0);
    }

#pragma unroll
    for (int j = 0; j < 2; ++j) {
        int col = n0 + j * 16 + cidx;
        float bv = bias[col];
#pragma unroll
        for (int i = 0; i < TM; ++i) {
#pragma unroll
            for (int r = 0; r < 4; ++r) {
                int row = m0 + i * 16 + kg * 4 + r;
                float val = (acc[i][j][r] + bv) * oscale;
                if (F32OUT) {
                    ((float*)Cp)[(long)row * DMODEL + col] = val;
                } else {
                    ((u16*)Cp)[(long)row * DMODEL + col] = f2bf(val);
                }
            }
        }
    }
}

__global__ __launch_bounds__(256) void qkv_gemm_kernel(
    const u16* __restrict__ Aqkv,
    const u16* __restrict__ wtall,
    const float* __restrict__ bq, const float* __restrict__ bk, const float* __restrict__ bv,
    u16* __restrict__ Q, u16* __restrict__ K, u16* __restrict__ V) {
    const u16* A = Aqkv + (long)blockIdx.z * 2097152;
    const u16* W = wtall + (long)(blockIdx.z + 1) * 262144;  // [wo, wq, wk, wv]
    const float* b;
    u16* C;
    float sc = 1.f;
    if (blockIdx.z == 0) { b = bq; C = Q; sc = QSCALE; }  // fold 1/sqrt(DH)*log2e into Q
    else if (blockIdx.z == 1) { b = bk; C = K; }
    else { b = bv; C = V; }
    gemm_body<false, 4>(A, W, b, C, sc);
}

__global__ __launch_bounds__(256) void out_gemm_kernel(const u16* __restrict__ A,
                                                       const u16* __restrict__ Wt,
                                                       const float* __restrict__ bias,
                                                       float* __restrict__ C) {
    gemm_body<true, 2>(A, Wt, bias, C, 1.f);
}

// ---------------- flash attention, S^T formulation ----------------
// grid: (S/64, B*H, KSPLIT), block 256 (4 waves). Wave w owns 16 q-rows (q = q0 + lane&15).
// QK^T computed transposed: D = K_tile . Q^T, so each lane holds 16 keys of ONE q-row.
// v2: double-buffered K/V LDS (ONE barrier per tile), 2-tile-deep register prefetch
// (T14 async-stage: loads issue 2 iters ahead, barrier section only ds_writes landed data),
// defer-max rescale (T13, THR=8 in exp2 domain -> P <= 2^8, safe in bf16),
// max3 reduction tree, s_setprio around MFMA clusters (T5).
__global__ __launch_bounds__(256) void attn_kernel(const u16* __restrict__ Q,
                                                   const u16* __restrict__ K,
                                                   const u16* __restrict__ Vt,
                                                   const float* __restrict__ mask,
                                                   const int* __restrict__ flags,
                                                   u16* __restrict__ Opart,
                                                   float* __restrict__ ML) {
    const int tid = threadIdx.x;
    const int lane = tid & 63;
    const int wave = tid >> 6;
    const int cidx = lane & 15;   // q-row (QK^T B-operand col / PV B-col); d-row for V A-frag
    const int kg = lane >> 4;
    const int bh = blockIdx.y;
    const int b = bh >> 3, h = bh & 7;
    const int q0 = blockIdx.x * 64 + wave * 16;
    const int z = blockIdx.z;
    const int k0z = z * KRANGE;

    __shared__ u16 kt_lds[2][64 * 64];   // [buf][key-local][dh], XOR-swizzled 8-blocks
    __shared__ u16 vt_lds[2][64 * 64];   // [buf][dh][key-local], XOR-swizzled
    __shared__ u16 p_lds[4][16 * 64];    // per-wave P^T as [q][key], XOR-swizzled
    u16* pw = p_lds[wave];

    // Q fragment: lane holds Q[q0+cidx][kg*8+j] (+32). Serves as B-operand of K.Q^T.
    const long qbase = ((long)(b * S_LEN + q0 + cidx)) * DMODEL + h * DHEAD + kg * 8;
    bf16x8 aq0 = ld8(Q + qbase);
    bf16x8 aq1 = ld8(Q + qbase + 32);

    const f32x4 fz = {0.f, 0.f, 0.f, 0.f};
    f32x4 acc[4];  // O^T accumulator: lane holds O[q0+cidx][16nt+4kg+r]
#pragma unroll
    for (int nt = 0; nt < 4; ++nt) acc[nt] = fz;
    float mrow = -1e30f;  // per-lane: one q-row (log2 domain, deferred-max reference)
    float lrow = 0.f;

    // staging roles: 512 16B slots over 256 threads
    const int krow0 = tid >> 3, kseg0 = tid & 7;  // rows 0..31
    const int krow1 = krow0 + 32;                 // rows 32..63
    const u16* kgbase = K + ((long)(b * S_LEN + k0z)) * DMODEL + h * DHEAD;
    const u16* vgbase = Vt + ((long)bh * DHEAD) * S_LEN + k0z;
    const int kd0 = krow0 * 64 + (((kseg0 ^ (krow0 & 7))) << 3);
    const int kd1 = krow1 * 64 + (((kseg0 ^ (krow1 & 7))) << 3);
    const int* flagrow = flags + b * 1024 + blockIdx.x * 32 + z * (KRANGE / 64);
    const int NIT = KRANGE / 64;

    const u16* kp0 = kgbase + (long)krow0 * DMODEL + kseg0 * 8;
    const u16* kp1 = kgbase + (long)krow1 * DMODEL + kseg0 * 8;
    const u16* vp0 = vgbase + (long)krow0 * S_LEN + kseg0 * 8;
    const u16* vp1 = vgbase + (long)krow1 * S_LEN + kseg0 * 8;

    // prologue: tile 0 -> buf0, prefetch tile 1 into regs
    u16x8 rk0 = *(const u16x8*)kp0;
    u16x8 rk1 = *(const u16x8*)kp1;
    u16x8 rv0 = *(const u16x8*)vp0;
    u16x8 rv1 = *(const u16x8*)vp1;
    *(u16x8*)&kt_lds[0][kd0] = rk0;
    *(u16x8*)&kt_lds[0][kd1] = rk1;
    *(u16x8*)&vt_lds[0][kd0] = rv0;
    *(u16x8*)&vt_lds[0][kd1] = rv1;
    rk0 = *(const u16x8*)(kp0 + 64 * DMODEL);
    rk1 = *(const u16x8*)(kp1 + 64 * DMODEL);
    rv0 = *(const u16x8*)(vp0 + 64);
    rv1 = *(const u16x8*)(vp1 + 64);
    __syncthreads();

    for (int it = 0; it < NIT; ++it) {
        const int cur = it & 1;
        // stage tile it+1 into the other buffer (regs landed >1 compute phase ago),
        // then issue tile it+2 global loads (hidden under this + next compute).
        if (it + 1 < NIT) {
            u16* kn = kt_lds[cur ^ 1];
            u16* vn = vt_lds[cur ^ 1];
            *(u16x8*)&kn[kd0] = rk0;
            *(u16x8*)&kn[kd1] = rk1;
            *(u16x8*)&vn[kd0] = rv0;
            *(u16x8*)&vn[kd1] = rv1;
            if (it + 2 < NIT) {
                const int t2 = (it + 2) * 64;
                rk0 = *(const u16x8*)(kp0 + (long)t2 * DMODEL);
                rk1 = *(const u16x8*)(kp1 + (long)t2 * DMODEL);
                rv0 = *(const u16x8*)(vp0 + t2);
                rv1 = *(const u16x8*)(vp1 + t2);
            }
        }
        const int flg = flagrow[it];
        const u16* kb = kt_lds[cur];
        const u16* vb = vt_lds[cur];

        // ---- S^T tile = K . Q^T : 64 keys x 16 q. Lane holds keys 16ct+4kg+r of q=q0+cidx.
        f32x4 sacc[4];
#pragma unroll
        for (int ct = 0; ct < 4; ++ct) sacc[ct] = fz;
        __builtin_amdgcn_s_setprio(1);
#pragma unroll
        for (int ct = 0; ct < 4; ++ct) {
            int r = ct * 16 + cidx;
            bf16x8 kv0 = ld8(&kb[r * 64 + ((kg ^ (r & 7)) << 3)]);
            bf16x8 kv1 = ld8(&kb[r * 64 + (((4 ^ kg) ^ (r & 7)) << 3)]);
            sacc[ct] = __builtin_amdgcn_mfma_f32_16x16x32_bf16(kv0, aq0, sacc[ct], 0, 0, 0);
            sacc[ct] = __builtin_amdgcn_mfma_f32_16x16x32_bf16(kv1, aq1, sacc[ct], 0, 0, 0);
        }
        __builtin_amdgcn_s_setprio(0);
        // mask slow path (rare): lane's q-row is fixed, keys contiguous -> f32x4 loads
        if (flg) {
            const float* mb = mask + ((long)(b * S_LEN + q0 + cidx)) * S_LEN + k0z + it * 64 + kg * 4;
#pragma unroll
            for (int ct = 0; ct < 4; ++ct) {
                f32x4 mv = *(const f32x4*)(mb + ct * 16);
#pragma unroll
                for (int r = 0; r < 4; ++r) sacc[ct][r] -= MASKC * mv[r];
            }
        }
        // ---- online softmax (exp2 domain), max3 tree + 2 shfls across kg ----
        float t0 = fmax3(sacc[0][0], sacc[0][1], sacc[0][2]);
        float t1 = fmax3(sacc[0][3], sacc[1][0], sacc[1][1]);
        float t2 = fmax3(sacc[1][2], sacc[1][3], sacc[2][0]);
        float t3 = fmax3(sacc[2][1], sacc[2][2], sacc[2][3]);
        float t4 = fmax3(sacc[3][0], sacc[3][1], sacc[3][2]);
        float mx = __builtin_fmaxf(fmax3(fmax3(t0, t1, t2), t3, t4), sacc[3][3]);
        mx = fmaxf(mx, __shfl_xor(mx, 16));
        mx = fmaxf(mx, __shfl_xor(mx, 32));
        // defer-max (T13): only rescale when the running reference is stale by >THR.
        // P stays bounded by 2^THR; combine() math is reference-point exact.
        if (mx > mrow + RESCALE_THR) {
            float mnew = fmaxf(mrow, mx);
            float alpha = exp2f(mrow - mnew);
            mrow = mnew;
            lrow *= alpha;
#pragma unroll
            for (int nt = 0; nt < 4; ++nt) acc[nt] = acc[nt] * alpha;
        }
        float s = 0.f;
#pragma unroll
        for (int ct = 0; ct < 4; ++ct)
#pragma unroll
            for (int r = 0; r < 4; ++r) {
                float pp = exp2f(sacc[ct][r] - mrow);
                sacc[ct][r] = pp;
                s += pp;
            }
        s += __shfl_xor(s, 16);
        s += __shfl_xor(s, 32);
        lrow += s;
        // ---- P^T -> per-wave LDS [q][key]: 4 packed b64 writes (keys 16ct+4kg..+3) ----
#pragma unroll
        for (int ct = 0; ct < 4; ++ct) {
            u32x2 d;
            d[0] = pk2bf(sacc[ct][0], sacc[ct][1]);
            d[1] = pk2bf(sacc[ct][2], sacc[ct][3]);
            int blk = 2 * ct + (kg >> 1);
            *(u32x2*)&pw[cidx * 64 + ((blk ^ (cidx & 7)) << 3) + (kg & 1) * 4] = d;
        }
        // B-frag of P^T: lane needs P[q=cidx][keys kg*8..+7] (and +32)
        bf16x8 pf0 = ld8(&pw[cidx * 64 + ((kg ^ (cidx & 7)) << 3)]);
        bf16x8 pf1 = ld8(&pw[cidx * 64 + (((4 ^ kg) ^ (cidx & 7)) << 3)]);
        // ---- O^T += V^T . P^T ----
        __builtin_amdgcn_s_setprio(1);
#pragma unroll
        for (int nt = 0; nt < 4; ++nt) {
            int rr = nt * 16 + cidx;
            bf16x8 v0 = ld8(&vb[rr * 64 + ((kg ^ (rr & 7)) << 3)]);
            bf16x8 v1 = ld8(&vb[rr * 64 + (((4 ^ kg) ^ (rr & 7)) << 3)]);
            acc[nt] = __builtin_amdgcn_mfma_f32_16x16x32_bf16(v0, pf0, acc[nt], 0, 0, 0);
            acc[nt] = __builtin_amdgcn_mfma_f32_16x16x32_bf16(v1, pf1, acc[nt], 0, 0, 0);
        }
        __builtin_amdgcn_s_setprio(0);
        __syncthreads();  // buf[cur^1] writes visible; all reads of buf[cur] complete
    }
    // epilogue: lane holds O[q0+cidx][16nt+4kg+r] -> packed 8B stores
    const long obase = (((long)(z * 16 + bh)) * S_LEN + q0 + cidx) * DHEAD;
#pragma unroll
    for (int nt = 0; nt < 4; ++nt) {
        u32x2 d;
        d[0] = pk2bf(acc[nt][0], acc[nt][1]);
        d[1] = pk2bf(acc[nt][2], acc[nt][3]);
        *(u32x2*)(Opart + obase + nt * 16 + kg * 4) = d;
    }
    if (lane < 16) {
        long mi = ((long)(z * 16 + bh)) * S_LEN + q0 + cidx;
        ML[mi * 2] = mrow;
        ML[mi * 2 + 1] = lrow;
    }
}

// combine KSPLIT partials -> merged bf16 (B,S,512). 8 cols/thread, 32 rows/block, grid 1024.
__global__ __launch_bounds__(256) void attn_combine_kernel(const u16* __restrict__ Opart,
                                                           const float* __restrict__ ML,
                                                           u16* __restrict__ Ab) {
    const int tid = threadIdx.x;
    const long rr = (long)blockIdx.x * 32 + (tid >> 3);  // bh*2048 + q
    const int c8 = (tid & 7) * 8;
    const int bh = (int)(rr >> 11);
    const int q = (int)(rr & 2047);
    const int b = bh >> 3, h = bh & 7;

    float m[KSPLIT], l[KSPLIT];
#pragma unroll
    for (int zz = 0; zz < KSPLIT; ++zz) {
        long mi = ((long)(zz * 16 + bh)) * S_LEN + q;
        m[zz] = ML[mi * 2];
        l[zz] = ML[mi * 2 + 1];
    }
    float M = m[0];
#pragma unroll
    for (int zz = 1; zz < KSPLIT; ++zz) M = fmaxf(M, m[zz]);
    float L = 0.f, e[KSPLIT];
#pragma unroll
    for (int zz = 0; zz < KSPLIT; ++zz) { e[zz] = exp2f(m[zz] - M); L += e[zz] * l[zz]; }
    float o[8] = {0, 0, 0, 0, 0, 0, 0, 0};
#pragma unroll
    for (int zz = 0; zz < KSPLIT; ++zz) {
        bf16x8 ov = ld8(Opart + (((long)(zz * 16 + bh)) * S_LEN + q) * DHEAD + c8);
#pragma unroll
        for (int j = 0; j < 8; ++j) o[j] += e[zz] * (float)ov[j];
    }
    float invL = 1.f / L;
    u16x8 w;
#pragma unroll
    for (int j = 0; j < 8; ++j) w[j] = f2bf(o[j] * invL);
    *(u16x8*)(Ab + ((long)(b * S_LEN + q)) * DMODEL + h * DHEAD + c8) = w;
}

extern "C" void kernel_launch(void* const* d_in, const int* in_sizes, int n_in,
                              void* d_out, int out_size, void* d_ws, size_t ws_size,
                              hipStream_t stream) {
    const float* q_in = (const float*)d_in[0];
    const float* k_in = (const float*)d_in[1];
    const float* v_in = (const float*)d_in[2];
    const float* mask = (const float*)d_in[3];
    const float* wq = (const float*)d_in[4];
    const float* bq = (const float*)d_in[5];
    const float* wk = (const float*)d_in[6];
    const float* bk = (const float*)d_in[7];
    const float* wv = (const float*)d_in[8];
    const float* bv = (const float*)d_in[9];
    const float* wo = (const float*)d_in[10];
    const float* bo = (const float*)d_in[11];

    // ws layout (u16 units). Regions ordered so attn can alias dead space:
    u16* ws = (u16*)d_ws;
    u16* Qb = ws;                       // 2.1M  projected Q (pre-scaled QSCALE)
    u16* Kb = Qb + 2097152;             // 2.1M
    u16* Vt = Kb + 2097152;             // 2.1M  V transposed (B,H,DH,S)
    u16* wtall = Vt + 2097152;          // 4 x 262144: [wo, wq, wk, wv]
    u16* Sreg = wtall + 4 * 262144;     // 3 x 2.1M: Aq,Ak,Av  (dead after qkv_gemm)
    u16* Vb = Sreg + 3 * 2097152;       // 2.1M  merged V    (dead after transpose_v)
    u16* Ab = Vb + 2097152;             // 2.1M  attention output (merged heads)
    int* mflags = (int*)(Ab + 2097152); // 2048 ints
    // aliases:
    u16* Opart = Sreg;                  // KSPLIT*16*2048*64 = 8.39M u16, spans Sreg+Vb ok
    float* ML = (float*)(wtall + 262144);  // over [wq,wk] slots (dead after qkv_gemm)

    prep_kernel<<<6144, 256, 0, stream>>>(q_in, k_in, v_in, wq, wk, wv, wo, mask,
                                          Sreg, wtall, mflags);
    qkv_gemm_kernel<<<dim3(8, 32, 3), 256, 0, stream>>>(Sreg, wtall, bq, bk, bv, Qb, Kb, Vb);
    transpose_v_kernel<<<dim3(2, 64, 16), dim3(32, 32), 0, stream>>>(Vb, Vt);
    attn_kernel<<<dim3(32, 16, KSPLIT), 256, 0, stream>>>(Qb, Kb, Vt, mask, mflags, Opart, ML);
    attn_combine_kernel<<<1024, 256, 0, stream>>>(Opart, ML, Ab);
    out_gemm_kernel<<<dim3(8, 64), 256, 0, stream>>>(Ab, wtall, bo, (float*)d_out);
}

// Round 3
// 209.128 us; speedup vs baseline: 1.1176x; 1.0519x over previous
//
#include <hip/hip_runtime.h>
#include <hip/hip_bf16.h>

typedef unsigned short u16;
typedef unsigned int u32;
typedef __bf16 bf16x8 __attribute__((ext_vector_type(8)));
typedef float f32x4 __attribute__((ext_vector_type(4)));
typedef u16 u16x8 __attribute__((ext_vector_type(8)));
typedef u32 u32x2 __attribute__((ext_vector_type(2)));

#define S_LEN 2048
#define DMODEL 512
#define NHEAD 8
#define DHEAD 64
#define KSPLIT 2
#define KRANGE (S_LEN / KSPLIT)  // 1024 k-positions per block
// log2(e); Q is pre-scaled by 0.125*LOG2E so softmax runs in exp2 domain.
#define QSCALE 0.1803368801111204f
#define MASKC 1.4426950409e9f
#define RESCALE_THR 8.0f

static __device__ __forceinline__ u16 f2bf(float f) {
    union { float f; unsigned u; } cv; cv.f = f;
    unsigned u = cv.u;
    return (u16)((u + 0x7fffu + ((u >> 16) & 1u)) >> 16);  // RNE
}
static __device__ __forceinline__ u32 pk2bf(float a, float b) {
    union { __hip_bfloat162 h; u32 u; } cv;
    float2 f2; f2.x = a; f2.y = b;
    cv.h = __float22bfloat162_rn(f2);
    return cv.u;
}
static __device__ __forceinline__ bf16x8 ld8(const u16* p) {
    return *(const bf16x8*)p;
}
static __device__ __forceinline__ float fmax3(float a, float b, float c) {
    return __builtin_fmaxf(__builtin_fmaxf(a, b), c);  // clang fuses to v_max3_f32
}

// ---------------- fused prep: qkv fp32->bf16 cvt | weight transpose->bf16 | mask flags ----
// grid.x partition: [0,3072) cvt, [3072,4096) transpose_w, [4096,6144) mask flags. 256 thr.
__global__ __launch_bounds__(256) void prep_kernel(
    const float* __restrict__ q, const float* __restrict__ k, const float* __restrict__ v,
    const float* __restrict__ w0, const float* __restrict__ w1,
    const float* __restrict__ w2, const float* __restrict__ w3,
    const float* __restrict__ mask,
    u16* __restrict__ Aqkv, u16* __restrict__ wtall, int* __restrict__ flags) {
    const int p = blockIdx.x;
    const int tid = threadIdx.x;
    __shared__ float t[32][33];
    __shared__ int wred[4];
    if (p < 3072) {
        const int z = p >> 10, px = p & 1023;
        const float* in = (z == 0) ? q : (z == 1) ? k : v;
        u16* o = Aqkv + (long)z * 2097152;
        long i = ((long)px * 256 + tid) * 8;
        f32x4 a = *(const f32x4*)(in + i);
        f32x4 b = *(const f32x4*)(in + i + 4);
        u16x8 r;
#pragma unroll
        for (int j = 0; j < 4; ++j) { r[j] = f2bf(a[j]); r[4 + j] = f2bf(b[j]); }
        *(u16x8*)(o + i) = r;
    } else if (p < 4096) {
        // W (512x512 fp32) -> Wt bf16 (N x K). slot order in wtall: [wo, wq, wk, wv]
        const int p2 = p - 3072;
        const int z = p2 >> 8, rem = p2 & 255, by = rem >> 4, bx = rem & 15;
        const float* in = (z == 0) ? w0 : (z == 1) ? w1 : (z == 2) ? w2 : w3;
        u16* o = wtall + (long)(((z + 1) & 3)) * 262144;
        const int tx = tid & 31, ty = tid >> 5;
#pragma unroll
        for (int i = 0; i < 4; ++i)
            t[ty + 8 * i][tx] = in[(by * 32 + ty + 8 * i) * DMODEL + bx * 32 + tx];
        __syncthreads();
#pragma unroll
        for (int i = 0; i < 4; ++i)
            o[(bx * 32 + ty + 8 * i) * DMODEL + by * 32 + tx] = f2bf(t[tx][ty + 8 * i]);
    } else {
        const int bid = p - 4096;  // 2*32*32
        const int b = bid >> 10, qt = (bid >> 5) & 31, kt = bid & 31;
        const int r = tid >> 2, cs = tid & 3;
        const float* mp = mask + ((long)(b * S_LEN + qt * 64 + r)) * S_LEN + kt * 64 + cs * 16;
        int nz = 0;
#pragma unroll
        for (int j = 0; j < 4; ++j) {
            f32x4 a = *(const f32x4*)(mp + j * 4);
            nz |= (a[0] != 0.f) | (a[1] != 0.f) | (a[2] != 0.f) | (a[3] != 0.f);
        }
        unsigned long long ball = __ballot(nz);
        if ((tid & 63) == 0) wred[tid >> 6] = (ball != 0ull) ? 1 : 0;
        __syncthreads();
        if (tid == 0) flags[bid] = wred[0] | wred[1] | wred[2] | wred[3];
    }
}

// ---------------- GEMM: C(4096x512) = A(4096x512) @ W + bias; block tile (TM*32) x 64,
// 4 waves (2x2), wave tile (TM*16) x 32. vtout: write C transposed per head into
// Vt (B,H,DH,S) with packed 8B stores (folds the old transpose_v kernel into the epilogue).
template <bool F32OUT, int TM>
static __device__ __forceinline__ void gemm_body(const u16* __restrict__ A,
                                                 const u16* __restrict__ Wt,
                                                 const float* __restrict__ bias,
                                                 void* __restrict__ Cp, float oscale,
                                                 bool vtout) {
    const int lane = threadIdx.x & 63;
    const int wave = threadIdx.x >> 6;
    const int wr = wave >> 1, wc = wave & 1;
    const int m0 = blockIdx.y * (TM * 32) + wr * (TM * 16);
    const int n0 = blockIdx.x * 64 + wc * 32;
    const int cidx = lane & 15;
    const int kg = lane >> 4;

    const u16* aptr[TM];
    const u16* bptr[2];
#pragma unroll
    for (int t = 0; t < TM; ++t)
        aptr[t] = A + (long)(m0 + t * 16 + cidx) * DMODEL + kg * 8;
#pragma unroll
    for (int t = 0; t < 2; ++t)
        bptr[t] = Wt + (long)(n0 + t * 16 + cidx) * DMODEL + kg * 8;

    const f32x4 fz = {0.f, 0.f, 0.f, 0.f};
    f32x4 acc[TM][2];
#pragma unroll
    for (int i = 0; i < TM; ++i)
#pragma unroll
        for (int j = 0; j < 2; ++j) acc[i][j] = fz;

#pragma unroll 4
    for (int k0 = 0; k0 < 512; k0 += 32) {
        bf16x8 a[TM], b[2];
#pragma unroll
        for (int t = 0; t < TM; ++t) a[t] = ld8(aptr[t] + k0);
#pragma unroll
        for (int t = 0; t < 2; ++t) b[t] = ld8(bptr[t] + k0);
#pragma unroll
        for (int i = 0; i < TM; ++i)
#pragma unroll
            for (int j = 0; j < 2; ++j)
                acc[i][j] = __builtin_amdgcn_mfma_f32_16x16x32_bf16(a[i], b[j], acc[i][j], 0, 0, 0);
    }

    if (vtout) {
        // V-transposed epilogue: row = token (b, s), col = channel (h, d).
        // Lane's 4 acc rows are consecutive tokens at fixed d -> one packed 8B store.
        const int bb = m0 >> 11;  // batch (tile never crosses the 2048 boundary)
#pragma unroll
        for (int j = 0; j < 2; ++j) {
            int col = n0 + j * 16 + cidx;
            float bv = bias[col];
            u16* vt = (u16*)Cp + (((long)(bb * 8 + (col >> 6))) * 64 + (col & 63)) * S_LEN;
#pragma unroll
            for (int i = 0; i < TM; ++i) {
                int s = (m0 + i * 16 + kg * 4) & (S_LEN - 1);
                u32x2 d;
                d[0] = pk2bf(acc[i][j][0] + bv, acc[i][j][1] + bv);
                d[1] = pk2bf(acc[i][j][2] + bv, acc[i][j][3] + bv);
                *(u32x2*)(vt + s) = d;
            }
        }
        return;
    }

#pragma unroll
    for (int j = 0; j < 2; ++j) {
        int col = n0 + j * 16 + cidx;
        float bv = bias[col];
#pragma unroll
        for (int i = 0; i < TM; ++i) {
#pragma unroll
            for (int r = 0; r < 4; ++r) {
                int row = m0 + i * 16 + kg * 4 + r;
                float val = (acc[i][j][r] + bv) * oscale;
                if (F32OUT) {
                    ((float*)Cp)[(long)row * DMODEL + col] = val;
                } else {
                    ((u16*)Cp)[(long)row * DMODEL + col] = f2bf(val);
                }
            }
        }
    }
}

__global__ __launch_bounds__(256) void qkv_gemm_kernel(
    const u16* __restrict__ Aqkv,
    const u16* __restrict__ wtall,
    const float* __restrict__ bq, const float* __restrict__ bk, const float* __restrict__ bv,
    u16* __restrict__ Q, u16* __restrict__ K, u16* __restrict__ Vt) {
    const u16* A = Aqkv + (long)blockIdx.z * 2097152;
    const u16* W = wtall + (long)(blockIdx.z + 1) * 262144;  // [wo, wq, wk, wv]
    const float* b;
    u16* C;
    float sc = 1.f;
    bool vt = false;
    if (blockIdx.z == 0) { b = bq; C = Q; sc = QSCALE; }  // fold 1/sqrt(DH)*log2e into Q
    else if (blockIdx.z == 1) { b = bk; C = K; }
    else { b = bv; C = Vt; vt = true; }
    gemm_body<false, 4>(A, W, b, C, sc, vt);
}

__global__ __launch_bounds__(256) void out_gemm_kernel(const u16* __restrict__ A,
                                                       const u16* __restrict__ Wt,
                                                       const float* __restrict__ bias,
                                                       float* __restrict__ C) {
    gemm_body<true, 2>(A, Wt, bias, C, 1.f, false);
}

// ---------------- flash attention, S^T formulation ----------------
// grid: (S/64, B*H, KSPLIT), block 256 (4 waves). Wave w owns 16 q-rows (q = q0 + lane&15).
// QK^T computed transposed: D = K_tile . Q^T, so each lane holds 16 keys of ONE q-row.
// v3: row-sum L computed by ones-row MFMA (accL) instead of 16 VALU adds + 2 shfls;
// double-buffered K/V LDS (ONE barrier per tile), 2-tile-deep register prefetch,
// defer-max rescale (THR=8, exp2 domain), max3 tree, s_setprio around MFMA clusters.
__global__ __launch_bounds__(256) void attn_kernel(const u16* __restrict__ Q,
                                                   const u16* __restrict__ K,
                                                   const u16* __restrict__ Vt,
                                                   const float* __restrict__ mask,
                                                   const int* __restrict__ flags,
                                                   u16* __restrict__ Opart,
                                                   float* __restrict__ ML) {
    const int tid = threadIdx.x;
    const int lane = tid & 63;
    const int wave = tid >> 6;
    const int cidx = lane & 15;   // q-row (QK^T B-operand col / PV B-col); d-row for V A-frag
    const int kg = lane >> 4;
    const int bh = blockIdx.y;
    const int b = bh >> 3, h = bh & 7;
    const int q0 = blockIdx.x * 64 + wave * 16;
    const int z = blockIdx.z;
    const int k0z = z * KRANGE;

    __shared__ u16 kt_lds[2][64 * 64];   // [buf][key-local][dh], XOR-swizzled 8-blocks
    __shared__ u16 vt_lds[2][64 * 64];   // [buf][dh][key-local], XOR-swizzled
    __shared__ u16 p_lds[4][16 * 64];    // per-wave P^T as [q][key], XOR-swizzled
    u16* pw = p_lds[wave];

    // Q fragment: lane holds Q[q0+cidx][kg*8+j] (+32). Serves as B-operand of K.Q^T.
    const long qbase = ((long)(b * S_LEN + q0 + cidx)) * DMODEL + h * DHEAD + kg * 8;
    bf16x8 aq0 = ld8(Q + qbase);
    bf16x8 aq1 = ld8(Q + qbase + 32);

    // ones A-fragment: row 0 = 1.0, rows 1..15 = 0. mfma(ones, P^T) row 0 = sum_k P[q][k].
    bf16x8 onesf;
    {
        u16x8 t8;
        u16 ob = (cidx == 0) ? (u16)0x3F80 : (u16)0;
#pragma unroll
        for (int j = 0; j < 8; ++j) t8[j] = ob;
        onesf = *(bf16x8*)&t8;
    }

    const f32x4 fz = {0.f, 0.f, 0.f, 0.f};
    f32x4 acc[4];  // O^T accumulator: lane holds O[q0+cidx][16nt+4kg+r]
#pragma unroll
    for (int nt = 0; nt < 4; ++nt) acc[nt] = fz;
    f32x4 accL = fz;      // lanes 0..15, comp 0: running sum L for q = q0+cidx
    float mrow = -1e30f;  // per-lane: one q-row (log2 domain, deferred-max reference)

    // staging roles: 512 16B slots over 256 threads
    const int krow0 = tid >> 3, kseg0 = tid & 7;  // rows 0..31
    const int krow1 = krow0 + 32;                 // rows 32..63
    const u16* kgbase = K + ((long)(b * S_LEN + k0z)) * DMODEL + h * DHEAD;
    const u16* vgbase = Vt + ((long)bh * DHEAD) * S_LEN + k0z;
    const int kd0 = krow0 * 64 + (((kseg0 ^ (krow0 & 7))) << 3);
    const int kd1 = krow1 * 64 + (((kseg0 ^ (krow1 & 7))) << 3);
    const int* flagrow = flags + b * 1024 + blockIdx.x * 32 + z * (KRANGE / 64);
    const int NIT = KRANGE / 64;

    const u16* kp0 = kgbase + (long)krow0 * DMODEL + kseg0 * 8;
    const u16* kp1 = kgbase + (long)krow1 * DMODEL + kseg0 * 8;
    const u16* vp0 = vgbase + (long)krow0 * S_LEN + kseg0 * 8;
    const u16* vp1 = vgbase + (long)krow1 * S_LEN + kseg0 * 8;

    // prologue: tile 0 -> buf0, prefetch tile 1 into regs
    u16x8 rk0 = *(const u16x8*)kp0;
    u16x8 rk1 = *(const u16x8*)kp1;
    u16x8 rv0 = *(const u16x8*)vp0;
    u16x8 rv1 = *(const u16x8*)vp1;
    *(u16x8*)&kt_lds[0][kd0] = rk0;
    *(u16x8*)&kt_lds[0][kd1] = rk1;
    *(u16x8*)&vt_lds[0][kd0] = rv0;
    *(u16x8*)&vt_lds[0][kd1] = rv1;
    rk0 = *(const u16x8*)(kp0 + 64 * DMODEL);
    rk1 = *(const u16x8*)(kp1 + 64 * DMODEL);
    rv0 = *(const u16x8*)(vp0 + 64);
    rv1 = *(const u16x8*)(vp1 + 64);
    __syncthreads();

    for (int it = 0; it < NIT; ++it) {
        const int cur = it & 1;
        // stage tile it+1 into the other buffer (regs landed >1 compute phase ago),
        // then issue tile it+2 global loads (hidden under this + next compute).
        if (it + 1 < NIT) {
            u16* kn = kt_lds[cur ^ 1];
            u16* vn = vt_lds[cur ^ 1];
            *(u16x8*)&kn[kd0] = rk0;
            *(u16x8*)&kn[kd1] = rk1;
            *(u16x8*)&vn[kd0] = rv0;
            *(u16x8*)&vn[kd1] = rv1;
            if (it + 2 < NIT) {
                const int t2 = (it + 2) * 64;
                rk0 = *(const u16x8*)(kp0 + (long)t2 * DMODEL);
                rk1 = *(const u16x8*)(kp1 + (long)t2 * DMODEL);
                rv0 = *(const u16x8*)(vp0 + t2);
                rv1 = *(const u16x8*)(vp1 + t2);
            }
        }
        const int flg = flagrow[it];
        const u16* kb = kt_lds[cur];
        const u16* vb = vt_lds[cur];

        // ---- S^T tile = K . Q^T : 64 keys x 16 q. Lane holds keys 16ct+4kg+r of q=q0+cidx.
        f32x4 sacc[4];
#pragma unroll
        for (int ct = 0; ct < 4; ++ct) sacc[ct] = fz;
        __builtin_amdgcn_s_setprio(1);
#pragma unroll
        for (int ct = 0; ct < 4; ++ct) {
            int r = ct * 16 + cidx;
            bf16x8 kv0 = ld8(&kb[r * 64 + ((kg ^ (r & 7)) << 3)]);
            bf16x8 kv1 = ld8(&kb[r * 64 + (((4 ^ kg) ^ (r & 7)) << 3)]);
            sacc[ct] = __builtin_amdgcn_mfma_f32_16x16x32_bf16(kv0, aq0, sacc[ct], 0, 0, 0);
            sacc[ct] = __builtin_amdgcn_mfma_f32_16x16x32_bf16(kv1, aq1, sacc[ct], 0, 0, 0);
        }
        __builtin_amdgcn_s_setprio(0);
        // mask slow path (rare): lane's q-row is fixed, keys contiguous -> f32x4 loads
        if (flg) {
            const float* mb = mask + ((long)(b * S_LEN + q0 + cidx)) * S_LEN + k0z + it * 64 + kg * 4;
#pragma unroll
            for (int ct = 0; ct < 4; ++ct) {
                f32x4 mv = *(const f32x4*)(mb + ct * 16);
#pragma unroll
                for (int r = 0; r < 4; ++r) sacc[ct][r] -= MASKC * mv[r];
            }
        }
        // ---- online softmax (exp2 domain), max3 tree + 2 shfls across kg ----
        float t0 = fmax3(sacc[0][0], sacc[0][1], sacc[0][2]);
        float t1 = fmax3(sacc[0][3], sacc[1][0], sacc[1][1]);
        float t2 = fmax3(sacc[1][2], sacc[1][3], sacc[2][0]);
        float t3 = fmax3(sacc[2][1], sacc[2][2], sacc[2][3]);
        float t4 = fmax3(sacc[3][0], sacc[3][1], sacc[3][2]);
        float mx = __builtin_fmaxf(fmax3(fmax3(t0, t1, t2), t3, t4), sacc[3][3]);
        mx = fmaxf(mx, __shfl_xor(mx, 16));
        mx = fmaxf(mx, __shfl_xor(mx, 32));
        // defer-max (T13): only rescale when the running reference is stale by >THR.
        // P stays bounded by 2^THR; combine() math is reference-point exact.
        if (mx > mrow + RESCALE_THR) {
            float mnew = fmaxf(mrow, mx);
            float alpha = __builtin_amdgcn_exp2f(mrow - mnew);
            mrow = mnew;
            accL = accL * alpha;
#pragma unroll
            for (int nt = 0; nt < 4; ++nt) acc[nt] = acc[nt] * alpha;
        }
#pragma unroll
        for (int ct = 0; ct < 4; ++ct)
#pragma unroll
            for (int r = 0; r < 4; ++r)
                sacc[ct][r] = __builtin_amdgcn_exp2f(sacc[ct][r] - mrow);
        // ---- P^T -> per-wave LDS [q][key]: 4 packed b64 writes (keys 16ct+4kg..+3) ----
#pragma unroll
        for (int ct = 0; ct < 4; ++ct) {
            u32x2 d;
            d[0] = pk2bf(sacc[ct][0], sacc[ct][1]);
            d[1] = pk2bf(sacc[ct][2], sacc[ct][3]);
            int blk = 2 * ct + (kg >> 1);
            *(u32x2*)&pw[cidx * 64 + ((blk ^ (cidx & 7)) << 3) + (kg & 1) * 4] = d;
        }
        // B-frag of P^T: lane needs P[q=cidx][keys kg*8..+7] (and +32)
        bf16x8 pf0 = ld8(&pw[cidx * 64 + ((kg ^ (cidx & 7)) << 3)]);
        bf16x8 pf1 = ld8(&pw[cidx * 64 + (((4 ^ kg) ^ (cidx & 7)) << 3)]);
        // ---- O^T += V^T . P^T ; L += ones . P^T (row-sum on the matrix pipe) ----
        __builtin_amdgcn_s_setprio(1);
#pragma unroll
        for (int nt = 0; nt < 4; ++nt) {
            int rr = nt * 16 + cidx;
            bf16x8 v0 = ld8(&vb[rr * 64 + ((kg ^ (rr & 7)) << 3)]);
            bf16x8 v1 = ld8(&vb[rr * 64 + (((4 ^ kg) ^ (rr & 7)) << 3)]);
            acc[nt] = __builtin_amdgcn_mfma_f32_16x16x32_bf16(v0, pf0, acc[nt], 0, 0, 0);
            acc[nt] = __builtin_amdgcn_mfma_f32_16x16x32_bf16(v1, pf1, acc[nt], 0, 0, 0);
        }
        accL = __builtin_amdgcn_mfma_f32_16x16x32_bf16(onesf, pf0, accL, 0, 0, 0);
        accL = __builtin_amdgcn_mfma_f32_16x16x32_bf16(onesf, pf1, accL, 0, 0, 0);
        __builtin_amdgcn_s_setprio(0);
        __syncthreads();  // buf[cur^1] writes visible; all reads of buf[cur] complete
    }
    // epilogue: lane holds O[q0+cidx][16nt+4kg+r] -> packed 8B stores
    const long obase = (((long)(z * 16 + bh)) * S_LEN + q0 + cidx) * DHEAD;
#pragma unroll
    for (int nt = 0; nt < 4; ++nt) {
        u32x2 d;
        d[0] = pk2bf(acc[nt][0], acc[nt][1]);
        d[1] = pk2bf(acc[nt][2], acc[nt][3]);
        *(u32x2*)(Opart + obase + nt * 16 + kg * 4) = d;
    }
    if (lane < 16) {
        long mi = ((long)(z * 16 + bh)) * S_LEN + q0 + cidx;
        ML[mi * 2] = mrow;
        ML[mi * 2 + 1] = accL[0];
    }
}

// combine KSPLIT partials -> merged bf16 (B,S,512). 8 cols/thread, 32 rows/block, grid 1024.
__global__ __launch_bounds__(256) void attn_combine_kernel(const u16* __restrict__ Opart,
                                                           const float* __restrict__ ML,
                                                           u16* __restrict__ Ab) {
    const int tid = threadIdx.x;
    const long rr = (long)blockIdx.x * 32 + (tid >> 3);  // bh*2048 + q
    const int c8 = (tid & 7) * 8;
    const int bh = (int)(rr >> 11);
    const int q = (int)(rr & 2047);
    const int b = bh >> 3, h = bh & 7;

    float m[KSPLIT], l[KSPLIT];
#pragma unroll
    for (int zz = 0; zz < KSPLIT; ++zz) {
        long mi = ((long)(zz * 16 + bh)) * S_LEN + q;
        m[zz] = ML[mi * 2];
        l[zz] = ML[mi * 2 + 1];
    }
    float M = m[0];
#pragma unroll
    for (int zz = 1; zz < KSPLIT; ++zz) M = fmaxf(M, m[zz]);
    float L = 0.f, e[KSPLIT];
#pragma unroll
    for (int zz = 0; zz < KSPLIT; ++zz) { e[zz] = exp2f(m[zz] - M); L += e[zz] * l[zz]; }
    float o[8] = {0, 0, 0, 0, 0, 0, 0, 0};
#pragma unroll
    for (int zz = 0; zz < KSPLIT; ++zz) {
        bf16x8 ov = ld8(Opart + (((long)(zz * 16 + bh)) * S_LEN + q) * DHEAD + c8);
#pragma unroll
        for (int j = 0; j < 8; ++j) o[j] += e[zz] * (float)ov[j];
    }
    float invL = 1.f / L;
    u16x8 w;
#pragma unroll
    for (int j = 0; j < 8; ++j) w[j] = f2bf(o[j] * invL);
    *(u16x8*)(Ab + ((long)(b * S_LEN + q)) * DMODEL + h * DHEAD + c8) = w;
}

extern "C" void kernel_launch(void* const* d_in, const int* in_sizes, int n_in,
                              void* d_out, int out_size, void* d_ws, size_t ws_size,
                              hipStream_t stream) {
    const float* q_in = (const float*)d_in[0];
    const float* k_in = (const float*)d_in[1];
    const float* v_in = (const float*)d_in[2];
    const float* mask = (const float*)d_in[3];
    const float* wq = (const float*)d_in[4];
    const float* bq = (const float*)d_in[5];
    const float* wk = (const float*)d_in[6];
    const float* bk = (const float*)d_in[7];
    const float* wv = (const float*)d_in[8];
    const float* bv = (const float*)d_in[9];
    const float* wo = (const float*)d_in[10];
    const float* bo = (const float*)d_in[11];

    // ws layout (u16 units). Regions ordered so attn can alias dead space:
    u16* ws = (u16*)d_ws;
    u16* Qb = ws;                       // 2.1M  projected Q (pre-scaled QSCALE)
    u16* Kb = Qb + 2097152;             // 2.1M
    u16* Vt = Kb + 2097152;             // 2.1M  V transposed (B,H,DH,S) - written by qkv_gemm
    u16* wtall = Vt + 2097152;          // 4 x 262144: [wo, wq, wk, wv]
    u16* Sreg = wtall + 4 * 262144;     // 3 x 2.1M: Aq,Ak,Av  (dead after qkv_gemm)
    u16* Ab = Sreg + 3 * 2097152;       // 2.1M  attention output (merged heads)
    int* mflags = (int*)(Ab + 2097152); // 2048 ints
    // aliases:
    u16* Opart = Sreg;                  // KSPLIT*16*2048*64 = 4.2M u16, fits in Sreg
    float* ML = (float*)(wtall + 262144);  // over [wq] slot (dead after qkv_gemm)

    prep_kernel<<<6144, 256, 0, stream>>>(q_in, k_in, v_in, wq, wk, wv, wo, mask,
                                          Sreg, wtall, mflags);
    qkv_gemm_kernel<<<dim3(8, 32, 3), 256, 0, stream>>>(Sreg, wtall, bq, bk, bv, Qb, Kb, Vt);
    attn_kernel<<<dim3(32, 16, KSPLIT), 256, 0, stream>>>(Qb, Kb, Vt, mask, mflags, Opart, ML);
    attn_combine_kernel<<<1024, 256, 0, stream>>>(Opart, ML, Ab);
    out_gemm_kernel<<<dim3(8, 64), 256, 0, stream>>>(Ab, wtall, bo, (float*)d_out);
}

// Round 4
// 202.187 us; speedup vs baseline: 1.1559x; 1.0343x over previous
//
#include <hip/hip_runtime.h>
#include <hip/hip_bf16.h>

typedef unsigned short u16;
typedef unsigned int u32;
typedef __bf16 bf16x8 __attribute__((ext_vector_type(8)));
typedef float f32x4 __attribute__((ext_vector_type(4)));
typedef u16 u16x8 __attribute__((ext_vector_type(8)));
typedef u32 u32x2 __attribute__((ext_vector_type(2)));

#define S_LEN 2048
#define DMODEL 512
#define NHEAD 8
#define DHEAD 64
// log2(e); Q is pre-scaled by 0.125*LOG2E so softmax runs in exp2 domain.
#define QSCALE 0.1803368801111204f
#define MASKC 1.4426950409e9f
#define RESCALE_THR 8.0f

static __device__ __forceinline__ u16 f2bf(float f) {
    union { float f; unsigned u; } cv; cv.f = f;
    unsigned u = cv.u;
    return (u16)((u + 0x7fffu + ((u >> 16) & 1u)) >> 16);  // RNE
}
static __device__ __forceinline__ u32 pk2bf(float a, float b) {
    union { __hip_bfloat162 h; u32 u; } cv;
    float2 f2; f2.x = a; f2.y = b;
    cv.h = __float22bfloat162_rn(f2);
    return cv.u;
}
static __device__ __forceinline__ bf16x8 ld8(const u16* p) {
    return *(const bf16x8*)p;
}
static __device__ __forceinline__ float fmax3(float a, float b, float c) {
    return __builtin_fmaxf(__builtin_fmaxf(a, b), c);  // clang fuses to v_max3_f32
}

// ---------------- fused prep: qkv fp32->bf16 cvt | weight transpose->bf16 | mask flags ----
// grid.x partition: [0,3072) cvt, [3072,4096) transpose_w, [4096,6144) mask flags. 256 thr.
__global__ __launch_bounds__(256) void prep_kernel(
    const float* __restrict__ q, const float* __restrict__ k, const float* __restrict__ v,
    const float* __restrict__ w0, const float* __restrict__ w1,
    const float* __restrict__ w2, const float* __restrict__ w3,
    const float* __restrict__ mask,
    u16* __restrict__ Aqkv, u16* __restrict__ wtall, int* __restrict__ flags) {
    const int p = blockIdx.x;
    const int tid = threadIdx.x;
    __shared__ float t[32][33];
    __shared__ int wred[4];
    if (p < 3072) {
        const int z = p >> 10, px = p & 1023;
        const float* in = (z == 0) ? q : (z == 1) ? k : v;
        u16* o = Aqkv + (long)z * 2097152;
        long i = ((long)px * 256 + tid) * 8;
        f32x4 a = *(const f32x4*)(in + i);
        f32x4 b = *(const f32x4*)(in + i + 4);
        u16x8 r;
#pragma unroll
        for (int j = 0; j < 4; ++j) { r[j] = f2bf(a[j]); r[4 + j] = f2bf(b[j]); }
        *(u16x8*)(o + i) = r;
    } else if (p < 4096) {
        // W (512x512 fp32) -> Wt bf16 (N x K). slot order in wtall: [wo, wq, wk, wv]
        const int p2 = p - 3072;
        const int z = p2 >> 8, rem = p2 & 255, by = rem >> 4, bx = rem & 15;
        const float* in = (z == 0) ? w0 : (z == 1) ? w1 : (z == 2) ? w2 : w3;
        u16* o = wtall + (long)(((z + 1) & 3)) * 262144;
        const int tx = tid & 31, ty = tid >> 5;
#pragma unroll
        for (int i = 0; i < 4; ++i)
            t[ty + 8 * i][tx] = in[(by * 32 + ty + 8 * i) * DMODEL + bx * 32 + tx];
        __syncthreads();
#pragma unroll
        for (int i = 0; i < 4; ++i)
            o[(bx * 32 + ty + 8 * i) * DMODEL + by * 32 + tx] = f2bf(t[tx][ty + 8 * i]);
    } else {
        const int bid = p - 4096;  // 2*32*32
        const int b = bid >> 10, qt = (bid >> 5) & 31, kt = bid & 31;
        const int r = tid >> 2, cs = tid & 3;
        const float* mp = mask + ((long)(b * S_LEN + qt * 64 + r)) * S_LEN + kt * 64 + cs * 16;
        int nz = 0;
#pragma unroll
        for (int j = 0; j < 4; ++j) {
            f32x4 a = *(const f32x4*)(mp + j * 4);
            nz |= (a[0] != 0.f) | (a[1] != 0.f) | (a[2] != 0.f) | (a[3] != 0.f);
        }
        unsigned long long ball = __ballot(nz);
        if ((tid & 63) == 0) wred[tid >> 6] = (ball != 0ull) ? 1 : 0;
        __syncthreads();
        if (tid == 0) flags[bid] = wred[0] | wred[1] | wred[2] | wred[3];
    }
}

// ---------------- GEMM: C(4096x512) = A(4096x512) @ W + bias; block tile (TM*32) x 64,
// 4 waves (2x2), wave tile (TM*16) x 32. bx/by are pre-swizzled (XCD-aware) tile indices.
// vtout: write C transposed per head into Vt (B,H,DH,S) with packed 8B stores.
template <bool F32OUT, int TM>
static __device__ __forceinline__ void gemm_body(const u16* __restrict__ A,
                                                 const u16* __restrict__ Wt,
                                                 const float* __restrict__ bias,
                                                 void* __restrict__ Cp, float oscale,
                                                 bool vtout, int bx, int by) {
    const int lane = threadIdx.x & 63;
    const int wave = threadIdx.x >> 6;
    const int wr = wave >> 1, wc = wave & 1;
    const int m0 = by * (TM * 32) + wr * (TM * 16);
    const int n0 = bx * 64 + wc * 32;
    const int cidx = lane & 15;
    const int kg = lane >> 4;

    const u16* aptr[TM];
    const u16* bptr[2];
#pragma unroll
    for (int t = 0; t < TM; ++t)
        aptr[t] = A + (long)(m0 + t * 16 + cidx) * DMODEL + kg * 8;
#pragma unroll
    for (int t = 0; t < 2; ++t)
        bptr[t] = Wt + (long)(n0 + t * 16 + cidx) * DMODEL + kg * 8;

    const f32x4 fz = {0.f, 0.f, 0.f, 0.f};
    f32x4 acc[TM][2];
#pragma unroll
    for (int i = 0; i < TM; ++i)
#pragma unroll
        for (int j = 0; j < 2; ++j) acc[i][j] = fz;

#pragma unroll 4
    for (int k0 = 0; k0 < 512; k0 += 32) {
        bf16x8 a[TM], b[2];
#pragma unroll
        for (int t = 0; t < TM; ++t) a[t] = ld8(aptr[t] + k0);
#pragma unroll
        for (int t = 0; t < 2; ++t) b[t] = ld8(bptr[t] + k0);
#pragma unroll
        for (int i = 0; i < TM; ++i)
#pragma unroll
            for (int j = 0; j < 2; ++j)
                acc[i][j] = __builtin_amdgcn_mfma_f32_16x16x32_bf16(a[i], b[j], acc[i][j], 0, 0, 0);
    }

    if (vtout) {
        // V-transposed epilogue: row = token (b, s), col = channel (h, d).
        // Lane's 4 acc rows are consecutive tokens at fixed d -> one packed 8B store.
        const int bb = m0 >> 11;  // batch (tile never crosses the 2048 boundary)
#pragma unroll
        for (int j = 0; j < 2; ++j) {
            int col = n0 + j * 16 + cidx;
            float bv = bias[col];
            u16* vt = (u16*)Cp + (((long)(bb * 8 + (col >> 6))) * 64 + (col & 63)) * S_LEN;
#pragma unroll
            for (int i = 0; i < TM; ++i) {
                int s = (m0 + i * 16 + kg * 4) & (S_LEN - 1);
                u32x2 d;
                d[0] = pk2bf(acc[i][j][0] + bv, acc[i][j][1] + bv);
                d[1] = pk2bf(acc[i][j][2] + bv, acc[i][j][3] + bv);
                *(u32x2*)(vt + s) = d;
            }
        }
        return;
    }

#pragma unroll
    for (int j = 0; j < 2; ++j) {
        int col = n0 + j * 16 + cidx;
        float bv = bias[col];
#pragma unroll
        for (int i = 0; i < TM; ++i) {
#pragma unroll
            for (int r = 0; r < 4; ++r) {
                int row = m0 + i * 16 + kg * 4 + r;
                float val = (acc[i][j][r] + bv) * oscale;
                if (F32OUT) {
                    ((float*)Cp)[(long)row * DMODEL + col] = val;
                } else {
                    ((u16*)Cp)[(long)row * DMODEL + col] = f2bf(val);
                }
            }
        }
    }
}

// XCD-aware swizzle (T1): dispatch order round-robins XCDs; remap so the 8 bx-blocks
// sharing one A row-panel all land on ONE XCD -> A panel fetched into that L2 once.
// Requires gridY % 8 == 0. Bijective: (xcd, j) <-> flat.
static __device__ __forceinline__ void xcd_swizzle(int gridX, int gridY, int& bx, int& by) {
    const int flat = blockIdx.x + gridX * blockIdx.y;
    const int xcd = flat & 7;
    const int j = flat >> 3;
    by = xcd * (gridY >> 3) + j / gridX;
    bx = j % gridX;
}

__global__ __launch_bounds__(256) void qkv_gemm_kernel(
    const u16* __restrict__ Aqkv,
    const u16* __restrict__ wtall,
    const float* __restrict__ bq, const float* __restrict__ bk, const float* __restrict__ bv,
    u16* __restrict__ Q, u16* __restrict__ K, u16* __restrict__ Vt) {
    const u16* A = Aqkv + (long)blockIdx.z * 2097152;
    const u16* W = wtall + (long)(blockIdx.z + 1) * 262144;  // [wo, wq, wk, wv]
    const float* b;
    u16* C;
    float sc = 1.f;
    bool vt = false;
    if (blockIdx.z == 0) { b = bq; C = Q; sc = QSCALE; }  // fold 1/sqrt(DH)*log2e into Q
    else if (blockIdx.z == 1) { b = bk; C = K; }
    else { b = bv; C = Vt; vt = true; }
    int bx, by;
    xcd_swizzle(8, 32, bx, by);
    gemm_body<false, 4>(A, W, b, C, sc, vt, bx, by);
}

__global__ __launch_bounds__(256) void out_gemm_kernel(const u16* __restrict__ A,
                                                       const u16* __restrict__ Wt,
                                                       const float* __restrict__ bias,
                                                       float* __restrict__ C) {
    int bx, by;
    xcd_swizzle(8, 64, bx, by);
    gemm_body<true, 2>(A, Wt, bias, C, 1.f, false, bx, by);
}

// ---------------- flash attention, S^T formulation ----------------
// grid: (S/64, B*H), block 256 (4 waves). Wave w owns 16 q-rows (q = q0 + lane&15).
// QK^T computed transposed: D = K_tile . Q^T, so each lane holds 16 keys of ONE q-row.
// v4: KSPLIT removed — full K-range per block, in-kernel normalization (acc * 1/L),
// writes merged bf16 Ab directly (no combine pass, no Opart/ML traffic).
// Row-sum L by ones-row MFMA; double-buffered K/V LDS; 2-tile-deep register prefetch;
// vote-based defer-max (common case: zero cross-lane reduce); setprio on MFMA clusters.
__global__ __launch_bounds__(256) void attn_kernel(const u16* __restrict__ Q,
                                                   const u16* __restrict__ K,
                                                   const u16* __restrict__ Vt,
                                                   const float* __restrict__ mask,
                                                   const int* __restrict__ flags,
                                                   u16* __restrict__ Ab) {
    const int tid = threadIdx.x;
    const int lane = tid & 63;
    const int wave = tid >> 6;
    const int cidx = lane & 15;   // q-row (QK^T B-operand col / PV B-col); d-row for V A-frag
    const int kg = lane >> 4;
    const int bh = blockIdx.y;
    const int b = bh >> 3, h = bh & 7;
    const int q0 = blockIdx.x * 64 + wave * 16;

    __shared__ u16 kt_lds[2][64 * 64];   // [buf][key-local][dh], XOR-swizzled 8-blocks
    __shared__ u16 vt_lds[2][64 * 64];   // [buf][dh][key-local], XOR-swizzled
    __shared__ u16 p_lds[4][16 * 64];    // per-wave P^T as [q][key], XOR-swizzled
    u16* pw = p_lds[wave];

    // Q fragment: lane holds Q[q0+cidx][kg*8+j] (+32). Serves as B-operand of K.Q^T.
    const long qbase = ((long)(b * S_LEN + q0 + cidx)) * DMODEL + h * DHEAD + kg * 8;
    bf16x8 aq0 = ld8(Q + qbase);
    bf16x8 aq1 = ld8(Q + qbase + 32);

    // ones A-fragment: row 0 = 1.0, rows 1..15 = 0. mfma(ones, P^T) row 0 = sum_k P[q][k].
    bf16x8 onesf;
    {
        u16x8 t8;
        u16 ob = (cidx == 0) ? (u16)0x3F80 : (u16)0;
#pragma unroll
        for (int j = 0; j < 8; ++j) t8[j] = ob;
        onesf = *(bf16x8*)&t8;
    }

    const f32x4 fz = {0.f, 0.f, 0.f, 0.f};
    f32x4 acc[4];  // O^T accumulator: lane holds O[q0+cidx][16nt+4kg+r]
#pragma unroll
    for (int nt = 0; nt < 4; ++nt) acc[nt] = fz;
    f32x4 accL = fz;      // after ones-MFMA: lane q (kg==0), comp 0 holds running L[q]
    float mrow = -1e30f;  // per-lane: one q-row (log2 domain, deferred-max reference)

    // staging roles: 512 16B slots over 256 threads
    const int krow0 = tid >> 3, kseg0 = tid & 7;  // rows 0..31
    const int krow1 = krow0 + 32;                 // rows 32..63
    const u16* kgbase = K + ((long)(b * S_LEN)) * DMODEL + h * DHEAD;
    const u16* vgbase = Vt + ((long)bh * DHEAD) * S_LEN;
    const int kd0 = krow0 * 64 + (((kseg0 ^ (krow0 & 7))) << 3);
    const int kd1 = krow1 * 64 + (((kseg0 ^ (krow1 & 7))) << 3);
    const int* flagrow = flags + b * 1024 + blockIdx.x * 32;
    const int NIT = S_LEN / 64;  // 32

    const u16* kp0 = kgbase + (long)krow0 * DMODEL + kseg0 * 8;
    const u16* kp1 = kgbase + (long)krow1 * DMODEL + kseg0 * 8;
    const u16* vp0 = vgbase + (long)krow0 * S_LEN + kseg0 * 8;
    const u16* vp1 = vgbase + (long)krow1 * S_LEN + kseg0 * 8;

    // prologue: tile 0 -> buf0, prefetch tile 1 into regs
    u16x8 rk0 = *(const u16x8*)kp0;
    u16x8 rk1 = *(const u16x8*)kp1;
    u16x8 rv0 = *(const u16x8*)vp0;
    u16x8 rv1 = *(const u16x8*)vp1;
    *(u16x8*)&kt_lds[0][kd0] = rk0;
    *(u16x8*)&kt_lds[0][kd1] = rk1;
    *(u16x8*)&vt_lds[0][kd0] = rv0;
    *(u16x8*)&vt_lds[0][kd1] = rv1;
    rk0 = *(const u16x8*)(kp0 + 64 * DMODEL);
    rk1 = *(const u16x8*)(kp1 + 64 * DMODEL);
    rv0 = *(const u16x8*)(vp0 + 64);
    rv1 = *(const u16x8*)(vp1 + 64);
    __syncthreads();

    for (int it = 0; it < NIT; ++it) {
        const int cur = it & 1;
        // stage tile it+1 into the other buffer (regs landed >1 compute phase ago),
        // then issue tile it+2 global loads (hidden under this + next compute).
        if (it + 1 < NIT) {
            u16* kn = kt_lds[cur ^ 1];
            u16* vn = vt_lds[cur ^ 1];
            *(u16x8*)&kn[kd0] = rk0;
            *(u16x8*)&kn[kd1] = rk1;
            *(u16x8*)&vn[kd0] = rv0;
            *(u16x8*)&vn[kd1] = rv1;
            if (it + 2 < NIT) {
                const int t2 = (it + 2) * 64;
                rk0 = *(const u16x8*)(kp0 + (long)t2 * DMODEL);
                rk1 = *(const u16x8*)(kp1 + (long)t2 * DMODEL);
                rv0 = *(const u16x8*)(vp0 + t2);
                rv1 = *(const u16x8*)(vp1 + t2);
            }
        }
        const int flg = flagrow[it];
        const u16* kb = kt_lds[cur];
        const u16* vb = vt_lds[cur];

        // ---- S^T tile = K . Q^T : 64 keys x 16 q. Lane holds keys 16ct+4kg+r of q=q0+cidx.
        f32x4 sacc[4];
#pragma unroll
        for (int ct = 0; ct < 4; ++ct) sacc[ct] = fz;
        __builtin_amdgcn_s_setprio(1);
#pragma unroll
        for (int ct = 0; ct < 4; ++ct) {
            int r = ct * 16 + cidx;
            bf16x8 kv0 = ld8(&kb[r * 64 + ((kg ^ (r & 7)) << 3)]);
            bf16x8 kv1 = ld8(&kb[r * 64 + (((4 ^ kg) ^ (r & 7)) << 3)]);
            sacc[ct] = __builtin_amdgcn_mfma_f32_16x16x32_bf16(kv0, aq0, sacc[ct], 0, 0, 0);
            sacc[ct] = __builtin_amdgcn_mfma_f32_16x16x32_bf16(kv1, aq1, sacc[ct], 0, 0, 0);
        }
        __builtin_amdgcn_s_setprio(0);
        // mask slow path (rare): lane's q-row is fixed, keys contiguous -> f32x4 loads
        if (flg) {
            const float* mb = mask + ((long)(b * S_LEN + q0 + cidx)) * S_LEN + it * 64 + kg * 4;
#pragma unroll
            for (int ct = 0; ct < 4; ++ct) {
                f32x4 mv = *(const f32x4*)(mb + ct * 16);
#pragma unroll
                for (int r = 0; r < 4; ++r) sacc[ct][r] -= MASKC * mv[r];
            }
        }
        // ---- online softmax (exp2 domain) ----
        // per-lane 16-key max (max3 tree); cross-lane reduce ONLY when a rescale is
        // actually needed (vote) — common case skips both shfls entirely.
        float t0 = fmax3(sacc[0][0], sacc[0][1], sacc[0][2]);
        float t1 = fmax3(sacc[0][3], sacc[1][0], sacc[1][1]);
        float t2 = fmax3(sacc[1][2], sacc[1][3], sacc[2][0]);
        float t3 = fmax3(sacc[2][1], sacc[2][2], sacc[2][3]);
        float t4 = fmax3(sacc[3][0], sacc[3][1], sacc[3][2]);
        float mxl = __builtin_fmaxf(fmax3(fmax3(t0, t1, t2), t3, t4), sacc[3][3]);
        if (__any(mxl > mrow + RESCALE_THR)) {
            float mx = fmaxf(mxl, __shfl_xor(mxl, 16));
            mx = fmaxf(mx, __shfl_xor(mx, 32));
            float mnew = fmaxf(mrow, mx);
            float alpha = __builtin_amdgcn_exp2f(mrow - mnew);
            mrow = mnew;
            accL = accL * alpha;
#pragma unroll
            for (int nt = 0; nt < 4; ++nt) acc[nt] = acc[nt] * alpha;
        }
#pragma unroll
        for (int ct = 0; ct < 4; ++ct)
#pragma unroll
            for (int r = 0; r < 4; ++r)
                sacc[ct][r] = __builtin_amdgcn_exp2f(sacc[ct][r] - mrow);
        // ---- P^T -> per-wave LDS [q][key]: 4 packed b64 writes (keys 16ct+4kg..+3) ----
#pragma unroll
        for (int ct = 0; ct < 4; ++ct) {
            u32x2 d;
            d[0] = pk2bf(sacc[ct][0], sacc[ct][1]);
            d[1] = pk2bf(sacc[ct][2], sacc[ct][3]);
            int blk = 2 * ct + (kg >> 1);
            *(u32x2*)&pw[cidx * 64 + ((blk ^ (cidx & 7)) << 3) + (kg & 1) * 4] = d;
        }
        // B-frag of P^T: lane needs P[q=cidx][keys kg*8..+7] (and +32)
        bf16x8 pf0 = ld8(&pw[cidx * 64 + ((kg ^ (cidx & 7)) << 3)]);
        bf16x8 pf1 = ld8(&pw[cidx * 64 + (((4 ^ kg) ^ (cidx & 7)) << 3)]);
        // ---- O^T += V^T . P^T ; L += ones . P^T (row-sum on the matrix pipe) ----
        __builtin_amdgcn_s_setprio(1);
#pragma unroll
        for (int nt = 0; nt < 4; ++nt) {
            int rr = nt * 16 + cidx;
            bf16x8 v0 = ld8(&vb[rr * 64 + ((kg ^ (rr & 7)) << 3)]);
            bf16x8 v1 = ld8(&vb[rr * 64 + (((4 ^ kg) ^ (rr & 7)) << 3)]);
            acc[nt] = __builtin_amdgcn_mfma_f32_16x16x32_bf16(v0, pf0, acc[nt], 0, 0, 0);
            acc[nt] = __builtin_amdgcn_mfma_f32_16x16x32_bf16(v1, pf1, acc[nt], 0, 0, 0);
        }
        accL = __builtin_amdgcn_mfma_f32_16x16x32_bf16(onesf, pf0, accL, 0, 0, 0);
        accL = __builtin_amdgcn_mfma_f32_16x16x32_bf16(onesf, pf1, accL, 0, 0, 0);
        __builtin_amdgcn_s_setprio(0);
        __syncthreads();  // buf[cur^1] writes visible; all reads of buf[cur] complete
    }
    // epilogue: L[q] sits in lane q (kg==0), comp 0 — broadcast, normalize, write bf16 Ab.
    float Lb = __shfl(accL[0], cidx);
    float invL = 1.f / Lb;
    const long abase = ((long)(b * S_LEN + q0 + cidx)) * DMODEL + h * DHEAD;
#pragma unroll
    for (int nt = 0; nt < 4; ++nt) {
        u32x2 d;
        d[0] = pk2bf(acc[nt][0] * invL, acc[nt][1] * invL);
        d[1] = pk2bf(acc[nt][2] * invL, acc[nt][3] * invL);
        *(u32x2*)(Ab + abase + nt * 16 + kg * 4) = d;
    }
}

extern "C" void kernel_launch(void* const* d_in, const int* in_sizes, int n_in,
                              void* d_out, int out_size, void* d_ws, size_t ws_size,
                              hipStream_t stream) {
    const float* q_in = (const float*)d_in[0];
    const float* k_in = (const float*)d_in[1];
    const float* v_in = (const float*)d_in[2];
    const float* mask = (const float*)d_in[3];
    const float* wq = (const float*)d_in[4];
    const float* bq = (const float*)d_in[5];
    const float* wk = (const float*)d_in[6];
    const float* bk = (const float*)d_in[7];
    const float* wv = (const float*)d_in[8];
    const float* bv = (const float*)d_in[9];
    const float* wo = (const float*)d_in[10];
    const float* bo = (const float*)d_in[11];

    // ws layout (u16 units):
    u16* ws = (u16*)d_ws;
    u16* Qb = ws;                       // 2.1M  projected Q (pre-scaled QSCALE)
    u16* Kb = Qb + 2097152;             // 2.1M
    u16* Vt = Kb + 2097152;             // 2.1M  V transposed (B,H,DH,S) - written by qkv_gemm
    u16* wtall = Vt + 2097152;          // 4 x 262144: [wo, wq, wk, wv]
    u16* Sreg = wtall + 4 * 262144;     // 3 x 2.1M: Aq,Ak,Av  (dead after qkv_gemm)
    u16* Ab = Sreg + 3 * 2097152;       // 2.1M  attention output (merged heads)
    int* mflags = (int*)(Ab + 2097152); // 2048 ints

    prep_kernel<<<6144, 256, 0, stream>>>(q_in, k_in, v_in, wq, wk, wv, wo, mask,
                                          Sreg, wtall, mflags);
    qkv_gemm_kernel<<<dim3(8, 32, 3), 256, 0, stream>>>(Sreg, wtall, bq, bk, bv, Qb, Kb, Vt);
    attn_kernel<<<dim3(32, 16), 256, 0, stream>>>(Qb, Kb, Vt, mask, mflags, Ab);
    out_gemm_kernel<<<dim3(8, 64), 256, 0, stream>>>(Ab, wtall, bo, (float*)d_out);
}